// Round 3
// baseline (2872.280 us; speedup 1.0000x reference)
//
#include <hip/hip_runtime.h>
#include <hip/hip_bf16.h>

typedef unsigned int u32;
typedef unsigned long long u64;

#define H_FM 100
#define W_FM 150
#define CIN 1024
#define CMID 512
#define NPIX 15000          // H_FM * W_FM
#define NANCH 135000        // NPIX * 9
#define PRE_NMS_N 6000
#define POST_NMS_N 300

typedef __attribute__((ext_vector_type(8))) short short8;
typedef __attribute__((ext_vector_type(8))) __bf16 bf16x8;
typedef __attribute__((ext_vector_type(4))) float f32x4;

__device__ __forceinline__ u32 fkey(float f) {
  u32 u = __float_as_uint(f);
  return (u & 0x80000000u) ? ~u : (u | 0x80000000u);
}

// MFMA wrapper: tolerate either short8 or bf16x8 builtin operand signature.
struct FragArg {
  short8 v;
  __device__ operator short8() const { return v; }
  __device__ operator bf16x8() const { return __builtin_bit_cast(bf16x8, v); }
};
__device__ __forceinline__ f32x4 mfma16(short8 a, short8 b, f32x4 c) {
  return __builtin_amdgcn_mfma_f32_16x16x32_bf16(FragArg{a}, FragArg{b}, c, 0, 0, 0);
}

#define GLL(gp, lp) __builtin_amdgcn_global_load_lds(                        \
    (const __attribute__((address_space(1))) unsigned int*)(gp),             \
    (__attribute__((address_space(3))) unsigned int*)(lp), 16, 0, 0)

// ---------------------------------------------------------------------------
// bf16x3 split of feature map + zero-page init.
// ---------------------------------------------------------------------------
__device__ __forceinline__ void split3(float f, unsigned short& a,
                                       unsigned short& b, unsigned short& c) {
  __hip_bfloat16 h0 = __float2bfloat16(f);
  float f0 = __bfloat162float(h0);
  float r1 = f - f0;
  __hip_bfloat16 h1 = __float2bfloat16(r1);
  float r2 = r1 - __bfloat162float(h1);
  __hip_bfloat16 h2 = __float2bfloat16(r2);
  a = *(unsigned short*)&h0;
  b = *(unsigned short*)&h1;
  c = *(unsigned short*)&h2;
}

__global__ __launch_bounds__(256) void k_split_fm(
    const float* __restrict__ src, unsigned short* __restrict__ d0,
    unsigned short* __restrict__ d1, unsigned short* __restrict__ d2,
    float* __restrict__ zp)
{
  if (blockIdx.x == 0 && threadIdx.x < 64) zp[threadIdx.x] = 0.f;
  const int n4 = NPIX * CIN / 4;
  for (int i = blockIdx.x * 256 + threadIdx.x; i < n4; i += gridDim.x * 256) {
    float4 v = ((const float4*)src)[i];
    float f[4] = {v.x, v.y, v.z, v.w};
    ushort4 o0, o1, o2;
    unsigned short* p0 = (unsigned short*)&o0;
    unsigned short* p1 = (unsigned short*)&o1;
    unsigned short* p2 = (unsigned short*)&o2;
    #pragma unroll
    for (int e = 0; e < 4; ++e) split3(f[e], p0[e], p1[e], p2[e]);
    ((ushort4*)d0)[i] = o0;
    ((ushort4*)d1)[i] = o1;
    ((ushort4*)d2)[i] = o2;
  }
}

// ---------------------------------------------------------------------------
// Split + transpose weights: W [9216 k][512 n] fp32 -> 3 bf16 planes [512 n][9216 k]
// ---------------------------------------------------------------------------
__global__ __launch_bounds__(256) void k_split_wt(
    const float* __restrict__ Wsrc, unsigned short* __restrict__ t0,
    unsigned short* __restrict__ t1, unsigned short* __restrict__ t2)
{
  __shared__ float tile[64][65];
  const int k0 = blockIdx.x * 64;   // 144 blocks
  const int n0 = blockIdx.y * 64;   // 8 blocks
  const int tid = threadIdx.x;
  const int lr = tid >> 4;
  const int lc = (tid & 15) * 4;
  #pragma unroll
  for (int rr = 0; rr < 64; rr += 16) {
    float4 v = *(const float4*)&Wsrc[(size_t)(k0 + lr + rr) * CMID + n0 + lc];
    tile[lr + rr][lc + 0] = v.x; tile[lr + rr][lc + 1] = v.y;
    tile[lr + rr][lc + 2] = v.z; tile[lr + rr][lc + 3] = v.w;
  }
  __syncthreads();
  const int n = tid >> 2;
  const int kk = (tid & 3) * 16;
  unsigned short b0[16], b1[16], b2[16];
  #pragma unroll
  for (int e = 0; e < 16; ++e) split3(tile[kk + e][n], b0[e], b1[e], b2[e]);
  size_t ob = ((size_t)(n0 + n) * 9216 + k0 + kk) >> 2;
  #pragma unroll
  for (int q = 0; q < 4; ++q) {
    ((ushort4*)t0)[ob + q] = *(ushort4*)&b0[q * 4];
    ((ushort4*)t1)[ob + q] = *(ushort4*)&b1[q * 4];
    ((ushort4*)t2)[ob + q] = *(ushort4*)&b2[q * 4];
  }
}

// ---------------------------------------------------------------------------
// MFMA conv with spatial-union A staging.
// M-tile = 5x25 pixels (125, padded to 128); union = 7x27 = 189 pixels.
// LDS A: [split 3][c 4][pix 192] x16B = 36864 B
// LDS B: [split 3][c 4][row 128] x16B = 24576 B  (offset 36864)
// ---------------------------------------------------------------------------
__global__ __launch_bounds__(256, 2) void k_conv5(
    const unsigned short* __restrict__ fm0, const unsigned short* __restrict__ fm1,
    const unsigned short* __restrict__ fm2, const unsigned short* __restrict__ wt0,
    const unsigned short* __restrict__ wt1, const unsigned short* __restrict__ wt2,
    const float* __restrict__ br, const float* __restrict__ zp,
    float* __restrict__ rpn)
{
  __shared__ char lds[61440];
  const int tid = threadIdx.x;
  const int lane = tid & 63;
  const int w = tid >> 6;
  const int bn = (blockIdx.x & 3) * 128;
  const int t = blockIdx.x >> 2;          // 120 spatial tiles
  const int ty = t / 6, tx = t - ty * 6;
  const int py0 = ty * 5, px0 = tx * 25;
  const int wm = (w >> 1) * 64, wn = (w & 1) * 64;

  const unsigned short* fmP[3] = {fm0, fm1, fm2};
  const unsigned short* wtP[3] = {wt0, wt1, wt2};

  // A staging: 36 jobs total, 9 per wave. job -> (split, c-chunk, pix-part)
  u64 asrc[9]; u32 amsk[9]; u32 adst[9];
  #pragma unroll
  for (int q = 0; q < 9; ++q) {
    int j36 = w * 9 + q;
    int s = j36 / 12, gg = j36 % 12;
    int c = gg / 3, part = gg - c * 3;
    int pix = part * 64 + lane;
    int uy = pix / 27, ux = pix - uy * 27;
    int gy = py0 + uy - 1, gx = px0 + ux - 1;
    bool valid = (pix < 189) && ((unsigned)gy < H_FM) && ((unsigned)gx < W_FM);
    asrc[q] = valid ? ((u64)(const char*)fmP[s] + (u64)(gy * W_FM + gx) * 2048 + c * 16)
                    : (u64)(const char*)zp;
    amsk[q] = valid ? 0xFFFFFFFFu : 0u;
    adst[q] = s * 12288 + c * 3072 + part * 1024;
  }
  // B staging: 24 jobs total, 6 per wave. job -> (split, c-chunk, row-part)
  u64 bsrc[6]; u32 bdst[6];
  #pragma unroll
  for (int q = 0; q < 6; ++q) {
    int j24 = w * 6 + q;
    int s = j24 >> 3, gg = j24 & 7;
    int c = gg >> 1, part = gg & 1;
    int row = part * 64 + lane;
    bsrc[q] = (u64)(const char*)wtP[s] + (u64)(bn + row) * 18432 + c * 16;
    bdst[q] = 36864u + s * 8192 + c * 2048 + part * 1024;
  }
  // fragment offsets
  int abase[4];
  #pragma unroll
  for (int i = 0; i < 4; ++i) {
    int m = wm + i * 16 + (lane & 15);
    int y = m / 25, x = m - y * 25;
    abase[i] = y * 27 + x + 28;   // union pixel at (y+1, x+1)
  }
  const int aquad = (lane >> 4) * 3072;
  u32 boff[3][4];
  #pragma unroll
  for (int s = 0; s < 3; ++s)
    #pragma unroll
    for (int j = 0; j < 4; ++j)
      boff[s][j] = 36864u + s * 8192 + (lane >> 4) * 2048 + (wn + j * 16 + (lane & 15)) * 16;

  f32x4 acc[4][4];
  #pragma unroll
  for (int i = 0; i < 4; ++i)
    #pragma unroll
    for (int j = 0; j < 4; ++j) acc[i][j] = (f32x4){0.f, 0.f, 0.f, 0.f};

  for (int chb = 0; chb < 2048; chb += 64) {     // 32 K-chunks (BK=32)
    __syncthreads();                              // prior reads of A/B done
    #pragma unroll
    for (int q = 0; q < 9; ++q)
      GLL((const char*)(asrc[q] + (u64)(chb & amsk[q])), lds + adst[q]);
    for (int seg = 0; seg < 9; ++seg) {
      if (seg) __syncthreads();                   // prior seg's B reads done
      const u32 so = (u32)(seg * 2048 + chb);
      #pragma unroll
      for (int q = 0; q < 6; ++q)
        GLL((const char*)(bsrc[q] + so), lds + bdst[q]);
      __syncthreads();                            // staging complete

      const int d = ((seg / 3) - 1) * 27 + (seg - (seg / 3) * 3 - 1);
      short8 B[3][4];
      #pragma unroll
      for (int s = 0; s < 3; ++s)
        #pragma unroll
        for (int j = 0; j < 4; ++j)
          B[s][j] = *(const short8*)(lds + boff[s][j]);
      #pragma unroll
      for (int i = 0; i < 4; ++i) {
        const int ap = (abase[i] + d) * 16 + aquad;
        short8 A0 = *(const short8*)(lds + ap);
        short8 A1 = *(const short8*)(lds + 12288 + ap);
        short8 A2 = *(const short8*)(lds + 24576 + ap);
        #pragma unroll
        for (int j = 0; j < 4; ++j) {
          f32x4 c = acc[i][j];
          c = mfma16(A0, B[0][j], c);
          c = mfma16(A0, B[1][j], c);
          c = mfma16(A1, B[0][j], c);
          c = mfma16(A1, B[1][j], c);
          c = mfma16(A0, B[2][j], c);
          c = mfma16(A2, B[0][j], c);
          acc[i][j] = c;
        }
      }
    }
  }

  // epilogue: bias + relu + store (C/D: row=(lane>>4)*4+reg, col=lane&15)
  #pragma unroll
  for (int i = 0; i < 4; ++i) {
    const int mb = wm + i * 16 + ((lane >> 4) << 2);
    #pragma unroll
    for (int r = 0; r < 4; ++r) {
      const int m = mb + r;
      if (m < 125) {
        int y = m / 25, x = m - y * 25;
        size_t gp = (size_t)((py0 + y) * W_FM + (px0 + x)) * CMID;
        #pragma unroll
        for (int j = 0; j < 4; ++j) {
          const int n = bn + wn + j * 16 + (lane & 15);
          rpn[gp + n] = fmaxf(acc[i][j][r] + br[n], 0.f);
        }
      }
    }
  }
}

// ---------------------------------------------------------------------------
// Pack head weights: Wp[512][64] (cls 0-17, bbox 18-53, pad), bp[64].
// ---------------------------------------------------------------------------
__global__ __launch_bounds__(256) void k_packW(
    const float* __restrict__ Ws, const float* __restrict__ bs,
    const float* __restrict__ Wb, const float* __restrict__ bb,
    float* __restrict__ Wp, float* __restrict__ bp)
{
  int tt = blockIdx.x * 256 + threadIdx.x;    // 128 blocks -> 32768
  int k = tt >> 6, o = tt & 63;
  float v = (o < 18) ? Ws[k * 18 + o] : ((o < 54) ? Wb[k * 36 + (o - 18)] : 0.f);
  Wp[tt] = v;
  if (tt < 64) bp[tt] = (tt < 18) ? bs[tt] : ((tt < 54) ? bb[tt - 18] : 0.f);
}

// ---------------------------------------------------------------------------
// Head GEMM: vals[M=15000][64] = rpn[M][512] * Wp[512][64] + bp.
// 118 blocks x 256 threads, M-tile 128, thread tile 4x8.
// ---------------------------------------------------------------------------
__global__ __launch_bounds__(256) void k_headgemm(
    const float* __restrict__ rpn, const float* __restrict__ Wp,
    const float* __restrict__ bp, float* __restrict__ vals)
{
  __shared__ float As[32][132];
  __shared__ float Bs[32][64];
  const int tid = threadIdx.x;
  const int bm = blockIdx.x * 128;
  const int mt = tid >> 3;          // 0..31 -> rows mt*4..+3
  const int nt = tid & 7;           // 0..7  -> cols nt*8..+7
  const int kg = tid & 7;           // A-load: float4 ch group
  const int ar = tid >> 3;          // A-load: row 0..31
  const int n4 = (tid & 15) * 4;    // B-load
  const int kr = tid >> 4;          // B-load row 0..15
  const float4 z4 = make_float4(0.f, 0.f, 0.f, 0.f);

  float acc[4][8];
  #pragma unroll
  for (int i = 0; i < 4; ++i)
    #pragma unroll
    for (int j = 0; j < 8; ++j) acc[i][j] = 0.f;

  for (int kc = 0; kc < 512; kc += 32) {
    __syncthreads();
    #pragma unroll
    for (int rr = 0; rr < 128; rr += 32) {
      int m = bm + ar + rr;
      float4 v = (m < NPIX) ? *(const float4*)&rpn[(size_t)m * CMID + kc + kg * 4] : z4;
      As[kg * 4 + 0][ar + rr] = v.x; As[kg * 4 + 1][ar + rr] = v.y;
      As[kg * 4 + 2][ar + rr] = v.z; As[kg * 4 + 3][ar + rr] = v.w;
    }
    *(float4*)&Bs[kr][n4]      = *(const float4*)&Wp[(kc + kr) * 64 + n4];
    *(float4*)&Bs[kr + 16][n4] = *(const float4*)&Wp[(kc + kr + 16) * 64 + n4];
    __syncthreads();
    #pragma unroll
    for (int kk = 0; kk < 32; ++kk) {
      float4 a = *(const float4*)&As[kk][mt * 4];
      float4 b0 = *(const float4*)&Bs[kk][nt * 8];
      float4 b1 = *(const float4*)&Bs[kk][nt * 8 + 4];
      float av[4] = {a.x, a.y, a.z, a.w};
      float bv[8] = {b0.x, b0.y, b0.z, b0.w, b1.x, b1.y, b1.z, b1.w};
      #pragma unroll
      for (int i = 0; i < 4; ++i)
        #pragma unroll
        for (int j = 0; j < 8; ++j) acc[i][j] = fmaf(av[i], bv[j], acc[i][j]);
    }
  }
  float bias[8];
  #pragma unroll
  for (int j = 0; j < 8; ++j) bias[j] = bp[nt * 8 + j];
  #pragma unroll
  for (int r = 0; r < 4; ++r) {
    int m = bm + mt * 4 + r;
    if (m < NPIX) {
      float o[8];
      #pragma unroll
      for (int j = 0; j < 8; ++j) o[j] = acc[r][j] + bias[j];
      float* op = vals + (size_t)m * 64 + nt * 8;
      *(float4*)op = *(float4*)&o[0];
      *(float4*)(op + 4) = *(float4*)&o[4];
    }
  }
}

// ---------------------------------------------------------------------------
// Decode: softmax + anchor decode + clip + min-size filter. 1 thread/anchor.
// ---------------------------------------------------------------------------
__global__ __launch_bounds__(256) void k_decode(
    const float* __restrict__ vals, const int* __restrict__ img,
    float* __restrict__ fg, float4* __restrict__ boxes)
{
  int gi = blockIdx.x * 256 + threadIdx.x;
  if (gi >= NANCH) return;
  const int p = gi / 9, a = gi - p * 9;
  const float AW[9] = {184.f, 368.f, 736.f, 128.f, 256.f, 512.f,  88.f, 176.f, 352.f};
  const float AH[9] = { 96.f, 192.f, 384.f, 128.f, 256.f, 512.f, 176.f, 352.f, 704.f};
  const int y = p / W_FM, x = p - y * W_FM;
  const float* row = vals + (size_t)p * 64;

  float c0 = row[2 * a], c1 = row[2 * a + 1];
  float score = 1.f / (1.f + expf(c0 - c1));

  float dxv = row[18 + 4 * a + 0];
  float dyv = row[18 + 4 * a + 1];
  float dwv = row[18 + 4 * a + 2];
  float dhv = row[18 + 4 * a + 3];

  float aw = AW[a], ah = AH[a];
  float acx = (float)(x * 16 + 8);
  float acy = (float)(y * 16 + 8);
  float pcx = dxv * aw + acx;
  float pcy = dyv * ah + acy;
  float pw = expf(dwv) * aw;
  float ph = expf(dhv) * ah;

  float imh1 = (float)img[0] - 1.f;
  float imw1 = (float)img[1] - 1.f;
  float b0 = fminf(fmaxf(pcx - 0.5f * pw, 0.f), imw1);
  float b1 = fminf(fmaxf(pcy - 0.5f * ph, 0.f), imh1);
  float b2 = fminf(fmaxf(pcx + 0.5f * pw, 0.f), imw1);
  float b3 = fminf(fmaxf(pcy + 0.5f * ph, 0.f), imh1);

  float bw = b2 - b0 + 1.f, bh = b3 - b1 + 1.f;
  if (!(bw >= 16.f && bh >= 16.f)) score = -1e9f;

  fg[gi] = score;
  boxes[gi] = make_float4(b0, b1, b2, b3);
}

// ---------------------------------------------------------------------------
// Radix-select (exact top-6000 threshold) machinery.
// ctl[0]=prefix/threshold, ctl[1]=kneed, ctl[2]=cntA, ctl[3]=cntB
// ---------------------------------------------------------------------------
__global__ void k_init(u32* __restrict__ hist, u32* __restrict__ ctl) {
  hist[threadIdx.x] = 0;
  if (threadIdx.x == 0) { ctl[0] = 0; ctl[1] = PRE_NMS_N; ctl[2] = 0; ctl[3] = 0; }
}

__global__ __launch_bounds__(256) void k_hist(
    const float* __restrict__ fg, u32* __restrict__ hist,
    const u32* __restrict__ ctl, int pass)
{
  __shared__ u32 h[256];
  h[threadIdx.x] = 0;
  __syncthreads();
  const int shift = 24 - 8 * pass;
  const u32 prefix = ctl[0];
  for (int i = blockIdx.x * 256 + threadIdx.x; i < NANCH; i += 128 * 256) {
    u32 key = fkey(fg[i]);
    bool match = (pass == 0) || ((key >> (shift + 8)) == prefix);
    if (match) atomicAdd(&h[(key >> shift) & 255], 1u);
  }
  __syncthreads();
  u32 c = h[threadIdx.x];
  if (c) atomicAdd(&hist[threadIdx.x], c);
}

__global__ void k_scan(u32* __restrict__ hist, u32* __restrict__ ctl) {
  if (threadIdx.x == 0) {
    u32 kneed = ctl[1];
    u32 cum = 0;
    int d = 0;
    for (int dd = 255; dd >= 0; --dd) {
      u32 c = hist[dd];
      if (cum + c >= kneed) { d = dd; break; }
      cum += c;
    }
    ctl[0] = (ctl[0] << 8) | (u32)d;
    ctl[1] = kneed - cum;
  }
  __syncthreads();
  hist[threadIdx.x] = 0;
}

__global__ __launch_bounds__(256) void k_compact(
    const float* __restrict__ fg, u32* __restrict__ ctl,
    u64* __restrict__ listA, u32* __restrict__ listB)
{
  int i = blockIdx.x * 256 + threadIdx.x;
  if (i >= NANCH) return;
  u32 T = ctl[0];
  u32 key = fkey(fg[i]);
  if (key > T) {
    u32 slot = atomicAdd(&ctl[2], 1u);
    listA[slot] = ((u64)key << 32) | (u64)(0xFFFFFFFFu - (u32)i);
  } else if (key == T) {
    u32 slot = atomicAdd(&ctl[3], 1u);
    if (slot < 8192) listB[slot] = (u32)i;
  }
}

__global__ __launch_bounds__(256) void k_tiefix(
    u32* __restrict__ ctl, const u32* __restrict__ listB, u64* __restrict__ listA)
{
  __shared__ u32 s[8192];
  const int tid = threadIdx.x;
  const u32 kneed = ctl[1];
  const u32 base = ctl[2];
  const u32 cntB = min(ctl[3], 8192u);
  const u32 T = ctl[0];
  if (kneed == 0) return;
  if (cntB == kneed) {
    for (u32 t = tid; t < kneed; t += 256)
      listA[base + t] = ((u64)T << 32) | (u64)(0xFFFFFFFFu - listB[t]);
    return;
  }
  u32 n2 = 1;
  while (n2 < cntB) n2 <<= 1;
  for (u32 i = tid; i < n2; i += 256) s[i] = (i < cntB) ? listB[i] : 0xFFFFFFFFu;
  __syncthreads();
  for (u32 k = 2; k <= n2; k <<= 1) {
    for (u32 j = k >> 1; j > 0; j >>= 1) {
      for (u32 i = tid; i < n2; i += 256) {
        u32 ixj = i ^ j;
        if (ixj > i) {
          u32 a = s[i], b = s[ixj];
          bool up = ((i & k) == 0);
          if ((a > b) == up) { s[i] = b; s[ixj] = a; }
        }
      }
      __syncthreads();
    }
  }
  for (u32 t = tid; t < kneed; t += 256)
    listA[base + t] = ((u64)T << 32) | (u64)(0xFFFFFFFFu - s[t]);
}

__global__ __launch_bounds__(1024) void k_sort(
    const u64* __restrict__ listA, u64* __restrict__ sorted)
{
  __shared__ u64 s[8192];
  const int tid = threadIdx.x;
  for (int i = tid; i < 8192; i += 1024) s[i] = (i < PRE_NMS_N) ? listA[i] : 0ull;
  __syncthreads();
  for (int k = 2; k <= 8192; k <<= 1) {
    for (int j = k >> 1; j > 0; j >>= 1) {
      for (int i = tid; i < 8192; i += 1024) {
        int ixj = i ^ j;
        if (ixj > i) {
          u64 a = s[i], b = s[ixj];
          bool up = ((i & k) == 0);
          if ((a < b) == up) { s[i] = b; s[ixj] = a; }
        }
      }
      __syncthreads();
    }
  }
  for (int i = tid; i < 8192; i += 1024) sorted[i] = s[i];
}

__global__ __launch_bounds__(256) void k_gather(
    const u64* __restrict__ sorted, const float4* __restrict__ boxes,
    float4* __restrict__ tb)
{
  int t = blockIdx.x * 256 + threadIdx.x;
  if (t >= PRE_NMS_N) return;
  u64 p = sorted[t];
  u32 idx = 0xFFFFFFFFu - (u32)(p & 0xFFFFFFFFull);
  tb[t] = boxes[idx];
}

// ---------------------------------------------------------------------------
// Block-parallel greedy NMS: LDS removed-bitmask, incremental suppression,
// early exit at 300 kept. Single block, 1024 threads.
// ---------------------------------------------------------------------------
__global__ __launch_bounds__(1024) void k_nms2(
    const u64* __restrict__ sorted, const float4* __restrict__ tb,
    float* __restrict__ out)
{
  __shared__ u32 rem[188];          // 6016 bits
  __shared__ int s_next;
  const int tid = threadIdx.x;
  const u32 kcut = fkey(-1e8f);
  const int BIG = 1 << 30;

  // init: invalid (filtered tail) & out-of-range marked removed
  for (int wd = tid; wd < 188; wd += 1024) {
    u32 m = 0;
    #pragma unroll 4
    for (int b = 0; b < 32; ++b) {
      int j = wd * 32 + b;
      if (j >= PRE_NMS_N || (u32)(sorted[j] >> 32) <= kcut) m |= (1u << b);
    }
    rem[wd] = m;
  }
  __syncthreads();

  int kept = 0;
  int cur = 0;
  for (;;) {
    // cooperative find-next from cur
    int found = -1;
    for (int b = cur; b < PRE_NMS_N; b += 1024) {
      if (tid == 0) s_next = BIG;
      __syncthreads();
      int idx = b + tid;
      if (idx < PRE_NMS_N && !((rem[idx >> 5] >> (idx & 31)) & 1u))
        atomicMin(&s_next, idx);
      __syncthreads();
      if (s_next != BIG) { found = s_next; break; }
    }
    if (found < 0) break;

    float4 bi = tb[found];
    if (tid < 4) out[kept * 4 + tid] = ((const float*)&tb[found])[tid];
    ++kept;
    if (kept >= POST_NMS_N) break;

    // suppress overlapping j > found
    const float ai = (bi.z - bi.x + 1.f) * (bi.w - bi.y + 1.f);
    for (int j = found + 1 + tid; j < PRE_NMS_N; j += 1024) {
      if (!((rem[j >> 5] >> (j & 31)) & 1u)) {
        float4 c = tb[j];
        float iw = fminf(bi.z, c.z) - fmaxf(bi.x, c.x) + 1.f;
        float ih = fminf(bi.w, c.w) - fmaxf(bi.y, c.y) + 1.f;
        float inter = fmaxf(iw, 0.f) * fmaxf(ih, 0.f);
        float aj = (c.z - c.x + 1.f) * (c.w - c.y + 1.f);
        float iou = inter / (ai + aj - inter);
        if (iou > 0.7f) atomicOr(&rem[j >> 5], 1u << (j & 31));
      }
    }
    __syncthreads();
    cur = found + 1;
  }
  // zero-fill tail
  for (int j = kept * 4 + tid; j < POST_NMS_N * 4; j += 1024) out[j] = 0.f;
}

// ---------------------------------------------------------------------------
extern "C" void kernel_launch(void* const* d_in, const int* in_sizes, int n_in,
                              void* d_out, int out_size, void* d_ws, size_t ws_size,
                              hipStream_t stream) {
  const float* fm  = (const float*)d_in[0];
  const float* Wr  = (const float*)d_in[1];
  const float* br  = (const float*)d_in[2];
  const float* Wsc = (const float*)d_in[3];
  const float* bsc = (const float*)d_in[4];
  const float* Wbb = (const float*)d_in[5];
  const float* bbb = (const float*)d_in[6];
  const int*   img = (const int*)d_in[7];
  float* out = (float*)d_out;

  char* w = (char*)d_ws;
  size_t off = 0;
  auto alloc = [&](size_t bytes) {
    size_t p = off;
    off = (off + bytes + 255) & ~(size_t)255;
    return p;
  };
  float* rpn    = (float*)(w + alloc((size_t)NPIX * CMID * 4));       // 30.72 MB
  float* fg     = (float*)(w + alloc((size_t)NANCH * 4));
  float4* boxes = (float4*)(w + alloc((size_t)NANCH * 16));
  u32* hist     = (u32*)(w + alloc(1024));
  u32* ctl      = (u32*)(w + alloc(64));
  u64* listA    = (u64*)(w + alloc((size_t)PRE_NMS_N * 8));
  u32* listB    = (u32*)(w + alloc(8192 * 4));
  u64* sorted   = (u64*)(w + alloc(8192 * 8));
  float4* topbox= (float4*)(w + alloc((size_t)PRE_NMS_N * 16));
  float* zp     = (float*)(w + alloc(256));
  float* Wp     = (float*)(w + alloc(512 * 64 * 4));
  float* bp     = (float*)(w + alloc(64 * 4));
  float* vals   = (float*)(w + alloc((size_t)NPIX * 64 * 4));         // 3.84 MB
  size_t fb = (size_t)NPIX * CIN * 2;
  size_t wb = (size_t)9216 * CMID * 2;
  unsigned short* fm0 = (unsigned short*)(w + alloc(fb));
  unsigned short* fm1 = (unsigned short*)(w + alloc(fb));
  unsigned short* fm2 = (unsigned short*)(w + alloc(fb));
  unsigned short* wt0 = (unsigned short*)(w + alloc(wb));
  unsigned short* wt1 = (unsigned short*)(w + alloc(wb));
  unsigned short* wt2 = (unsigned short*)(w + alloc(wb));

  // 1. precision-split + transpose + pack
  k_split_fm<<<dim3(1024), dim3(256), 0, stream>>>(fm, fm0, fm1, fm2, zp);
  k_split_wt<<<dim3(144, 8), dim3(256), 0, stream>>>(Wr, wt0, wt1, wt2);
  k_packW<<<dim3(128), dim3(256), 0, stream>>>(Wsc, bsc, Wbb, bbb, Wp, bp);
  // 2. conv (3x3 + bias + relu), spatial-union MFMA
  k_conv5<<<dim3(120 * 4), dim3(256), 0, stream>>>(
      fm0, fm1, fm2, wt0, wt1, wt2, br, zp, rpn);
  // 3. heads + decode
  k_headgemm<<<dim3(118), dim3(256), 0, stream>>>(rpn, Wp, bp, vals);
  k_decode<<<dim3((NANCH + 255) / 256), dim3(256), 0, stream>>>(vals, img, fg, boxes);
  // 4. exact top-6000 radix select
  k_init<<<1, 256, 0, stream>>>(hist, ctl);
  for (int pass = 0; pass < 4; ++pass) {
    k_hist<<<128, 256, 0, stream>>>(fg, hist, ctl, pass);
    k_scan<<<1, 256, 0, stream>>>(hist, ctl);
  }
  k_compact<<<(NANCH + 255) / 256, 256, 0, stream>>>(fg, ctl, listA, listB);
  k_tiefix<<<1, 256, 0, stream>>>(ctl, listB, listA);
  // 5. sort (desc score, asc index) + gather
  k_sort<<<1, 1024, 0, stream>>>(listA, sorted);
  k_gather<<<(PRE_NMS_N + 255) / 256, 256, 0, stream>>>(sorted, boxes, topbox);
  // 6. block-parallel greedy NMS + emit 300
  k_nms2<<<1, 1024, 0, stream>>>(sorted, topbox, out);
}

// Round 4
// 1407.807 us; speedup vs baseline: 2.0403x; 2.0403x over previous
//
#include <hip/hip_runtime.h>
#include <hip/hip_bf16.h>

typedef unsigned int u32;
typedef unsigned long long u64;

#define H_FM 100
#define W_FM 150
#define CIN 1024
#define CMID 512
#define NPIX 15000          // H_FM * W_FM
#define NANCH 135000        // NPIX * 9
#define PRE_NMS_N 6000
#define POST_NMS_N 300
#define WPR 94              // ceil(6000/64) words per mask row

typedef __attribute__((ext_vector_type(8))) short short8;
typedef __attribute__((ext_vector_type(8))) __bf16 bf16x8;
typedef __attribute__((ext_vector_type(4))) float f32x4;

__device__ __forceinline__ u32 fkey(float f) {
  u32 u = __float_as_uint(f);
  return (u & 0x80000000u) ? ~u : (u | 0x80000000u);
}

__device__ __forceinline__ u64 shfl64(u64 v, int src) {
  u32 lo = (u32)__shfl((int)(u32)v, src, 64);
  u32 hi = (u32)__shfl((int)(u32)(v >> 32), src, 64);
  return ((u64)hi << 32) | (u64)lo;
}

// MFMA wrapper: tolerate either short8 or bf16x8 builtin operand signature.
struct FragArg {
  short8 v;
  __device__ operator short8() const { return v; }
  __device__ operator bf16x8() const { return __builtin_bit_cast(bf16x8, v); }
};
__device__ __forceinline__ f32x4 mfma16(short8 a, short8 b, f32x4 c) {
  return __builtin_amdgcn_mfma_f32_16x16x32_bf16(FragArg{a}, FragArg{b}, c, 0, 0, 0);
}

#define GLL(gp, lp) __builtin_amdgcn_global_load_lds(                        \
    (const __attribute__((address_space(1))) unsigned int*)(gp),             \
    (__attribute__((address_space(3))) unsigned int*)(lp), 16, 0, 0)

// ---------------------------------------------------------------------------
// bf16x3 split of feature map + zero-page init.
// ---------------------------------------------------------------------------
__device__ __forceinline__ void split3(float f, unsigned short& a,
                                       unsigned short& b, unsigned short& c) {
  __hip_bfloat16 h0 = __float2bfloat16(f);
  float f0 = __bfloat162float(h0);
  float r1 = f - f0;
  __hip_bfloat16 h1 = __float2bfloat16(r1);
  float r2 = r1 - __bfloat162float(h1);
  __hip_bfloat16 h2 = __float2bfloat16(r2);
  a = *(unsigned short*)&h0;
  b = *(unsigned short*)&h1;
  c = *(unsigned short*)&h2;
}

__global__ __launch_bounds__(256) void k_split_fm(
    const float* __restrict__ src, unsigned short* __restrict__ d0,
    unsigned short* __restrict__ d1, unsigned short* __restrict__ d2,
    float* __restrict__ zp)
{
  if (blockIdx.x == 0 && threadIdx.x < 64) zp[threadIdx.x] = 0.f;
  const int n4 = NPIX * CIN / 4;
  for (int i = blockIdx.x * 256 + threadIdx.x; i < n4; i += gridDim.x * 256) {
    float4 v = ((const float4*)src)[i];
    float f[4] = {v.x, v.y, v.z, v.w};
    ushort4 o0, o1, o2;
    unsigned short* p0 = (unsigned short*)&o0;
    unsigned short* p1 = (unsigned short*)&o1;
    unsigned short* p2 = (unsigned short*)&o2;
    #pragma unroll
    for (int e = 0; e < 4; ++e) split3(f[e], p0[e], p1[e], p2[e]);
    ((ushort4*)d0)[i] = o0;
    ((ushort4*)d1)[i] = o1;
    ((ushort4*)d2)[i] = o2;
  }
}

// ---------------------------------------------------------------------------
// Split + transpose weights: W [9216 k][512 n] fp32 -> 3 bf16 planes [512 n][9216 k]
// ---------------------------------------------------------------------------
__global__ __launch_bounds__(256) void k_split_wt(
    const float* __restrict__ Wsrc, unsigned short* __restrict__ t0,
    unsigned short* __restrict__ t1, unsigned short* __restrict__ t2)
{
  __shared__ float tile[64][65];
  const int k0 = blockIdx.x * 64;   // 144 blocks
  const int n0 = blockIdx.y * 64;   // 8 blocks
  const int tid = threadIdx.x;
  const int lr = tid >> 4;
  const int lc = (tid & 15) * 4;
  #pragma unroll
  for (int rr = 0; rr < 64; rr += 16) {
    float4 v = *(const float4*)&Wsrc[(size_t)(k0 + lr + rr) * CMID + n0 + lc];
    tile[lr + rr][lc + 0] = v.x; tile[lr + rr][lc + 1] = v.y;
    tile[lr + rr][lc + 2] = v.z; tile[lr + rr][lc + 3] = v.w;
  }
  __syncthreads();
  const int n = tid >> 2;
  const int kk = (tid & 3) * 16;
  unsigned short b0[16], b1[16], b2[16];
  #pragma unroll
  for (int e = 0; e < 16; ++e) split3(tile[kk + e][n], b0[e], b1[e], b2[e]);
  size_t ob = ((size_t)(n0 + n) * 9216 + k0 + kk) >> 2;
  #pragma unroll
  for (int q = 0; q < 4; ++q) {
    ((ushort4*)t0)[ob + q] = *(ushort4*)&b0[q * 4];
    ((ushort4*)t1)[ob + q] = *(ushort4*)&b1[q * 4];
    ((ushort4*)t2)[ob + q] = *(ushort4*)&b2[q * 4];
  }
}

// ---------------------------------------------------------------------------
// MFMA conv with spatial-union A staging.
// M-tile = 5x25 pixels (125, padded to 128); union = 7x27 = 189 pixels.
// LDS A: [split 3][c 4][pix 192] x16B = 36864 B
// LDS B: [split 3][c 4][row 128] x16B = 24576 B  (offset 36864)
// ---------------------------------------------------------------------------
__global__ __launch_bounds__(256, 2) void k_conv5(
    const unsigned short* __restrict__ fm0, const unsigned short* __restrict__ fm1,
    const unsigned short* __restrict__ fm2, const unsigned short* __restrict__ wt0,
    const unsigned short* __restrict__ wt1, const unsigned short* __restrict__ wt2,
    const float* __restrict__ br, const float* __restrict__ zp,
    float* __restrict__ rpn)
{
  __shared__ char lds[61440];
  const int tid = threadIdx.x;
  const int lane = tid & 63;
  const int w = tid >> 6;
  const int bn = (blockIdx.x & 3) * 128;
  const int t = blockIdx.x >> 2;          // 120 spatial tiles
  const int ty = t / 6, tx = t - ty * 6;
  const int py0 = ty * 5, px0 = tx * 25;
  const int wm = (w >> 1) * 64, wn = (w & 1) * 64;

  const unsigned short* fmP[3] = {fm0, fm1, fm2};
  const unsigned short* wtP[3] = {wt0, wt1, wt2};

  // A staging: 36 jobs total, 9 per wave. job -> (split, c-chunk, pix-part)
  u64 asrc[9]; u32 amsk[9]; u32 adst[9];
  #pragma unroll
  for (int q = 0; q < 9; ++q) {
    int j36 = w * 9 + q;
    int s = j36 / 12, gg = j36 % 12;
    int c = gg / 3, part = gg - c * 3;
    int pix = part * 64 + lane;
    int uy = pix / 27, ux = pix - uy * 27;
    int gy = py0 + uy - 1, gx = px0 + ux - 1;
    bool valid = (pix < 189) && ((unsigned)gy < H_FM) && ((unsigned)gx < W_FM);
    asrc[q] = valid ? ((u64)(const char*)fmP[s] + (u64)(gy * W_FM + gx) * 2048 + c * 16)
                    : (u64)(const char*)zp;
    amsk[q] = valid ? 0xFFFFFFFFu : 0u;
    adst[q] = s * 12288 + c * 3072 + part * 1024;
  }
  // B staging: 24 jobs total, 6 per wave. job -> (split, c-chunk, row-part)
  u64 bsrc[6]; u32 bdst[6];
  #pragma unroll
  for (int q = 0; q < 6; ++q) {
    int j24 = w * 6 + q;
    int s = j24 >> 3, gg = j24 & 7;
    int c = gg >> 1, part = gg & 1;
    int row = part * 64 + lane;
    bsrc[q] = (u64)(const char*)wtP[s] + (u64)(bn + row) * 18432 + c * 16;
    bdst[q] = 36864u + s * 8192 + c * 2048 + part * 1024;
  }
  // fragment offsets
  int abase[4];
  #pragma unroll
  for (int i = 0; i < 4; ++i) {
    int m = wm + i * 16 + (lane & 15);
    int y = m / 25, x = m - y * 25;
    abase[i] = y * 27 + x + 28;   // union pixel at (y+1, x+1)
  }
  const int aquad = (lane >> 4) * 3072;
  u32 boff[3][4];
  #pragma unroll
  for (int s = 0; s < 3; ++s)
    #pragma unroll
    for (int j = 0; j < 4; ++j)
      boff[s][j] = 36864u + s * 8192 + (lane >> 4) * 2048 + (wn + j * 16 + (lane & 15)) * 16;

  f32x4 acc[4][4];
  #pragma unroll
  for (int i = 0; i < 4; ++i)
    #pragma unroll
    for (int j = 0; j < 4; ++j) acc[i][j] = (f32x4){0.f, 0.f, 0.f, 0.f};

  for (int chb = 0; chb < 2048; chb += 64) {     // 32 K-chunks (BK=32)
    __syncthreads();                              // prior reads of A/B done
    #pragma unroll
    for (int q = 0; q < 9; ++q)
      GLL((const char*)(asrc[q] + (u64)(chb & amsk[q])), lds + adst[q]);
    for (int seg = 0; seg < 9; ++seg) {
      if (seg) __syncthreads();                   // prior seg's B reads done
      const u32 so = (u32)(seg * 2048 + chb);
      #pragma unroll
      for (int q = 0; q < 6; ++q)
        GLL((const char*)(bsrc[q] + so), lds + bdst[q]);
      __syncthreads();                            // staging complete

      const int d = ((seg / 3) - 1) * 27 + (seg - (seg / 3) * 3 - 1);
      short8 B[3][4];
      #pragma unroll
      for (int s = 0; s < 3; ++s)
        #pragma unroll
        for (int j = 0; j < 4; ++j)
          B[s][j] = *(const short8*)(lds + boff[s][j]);
      #pragma unroll
      for (int i = 0; i < 4; ++i) {
        const int ap = (abase[i] + d) * 16 + aquad;
        short8 A0 = *(const short8*)(lds + ap);
        short8 A1 = *(const short8*)(lds + 12288 + ap);
        short8 A2 = *(const short8*)(lds + 24576 + ap);
        #pragma unroll
        for (int j = 0; j < 4; ++j) {
          f32x4 c = acc[i][j];
          c = mfma16(A0, B[0][j], c);
          c = mfma16(A0, B[1][j], c);
          c = mfma16(A1, B[0][j], c);
          c = mfma16(A1, B[1][j], c);
          c = mfma16(A0, B[2][j], c);
          c = mfma16(A2, B[0][j], c);
          acc[i][j] = c;
        }
      }
    }
  }

  // epilogue: bias + relu + store (C/D: row=(lane>>4)*4+reg, col=lane&15)
  #pragma unroll
  for (int i = 0; i < 4; ++i) {
    const int mb = wm + i * 16 + ((lane >> 4) << 2);
    #pragma unroll
    for (int r = 0; r < 4; ++r) {
      const int m = mb + r;
      if (m < 125) {
        int y = m / 25, x = m - y * 25;
        size_t gp = (size_t)((py0 + y) * W_FM + (px0 + x)) * CMID;
        #pragma unroll
        for (int j = 0; j < 4; ++j) {
          const int n = bn + wn + j * 16 + (lane & 15);
          rpn[gp + n] = fmaxf(acc[i][j][r] + br[n], 0.f);
        }
      }
    }
  }
}

// ---------------------------------------------------------------------------
// Pack head weights: Wp[512][64] (cls 0-17, bbox 18-53, pad), bp[64].
// ---------------------------------------------------------------------------
__global__ __launch_bounds__(256) void k_packW(
    const float* __restrict__ Ws, const float* __restrict__ bs,
    const float* __restrict__ Wb, const float* __restrict__ bb,
    float* __restrict__ Wp, float* __restrict__ bp)
{
  int tt = blockIdx.x * 256 + threadIdx.x;    // 128 blocks -> 32768
  int k = tt >> 6, o = tt & 63;
  float v = (o < 18) ? Ws[k * 18 + o] : ((o < 54) ? Wb[k * 36 + (o - 18)] : 0.f);
  Wp[tt] = v;
  if (tt < 64) bp[tt] = (tt < 18) ? bs[tt] : ((tt < 54) ? bb[tt - 18] : 0.f);
}

// ---------------------------------------------------------------------------
// Head GEMM: vals[M=15000][64] = rpn[M][512] * Wp[512][64] + bp.
// ---------------------------------------------------------------------------
__global__ __launch_bounds__(256) void k_headgemm(
    const float* __restrict__ rpn, const float* __restrict__ Wp,
    const float* __restrict__ bp, float* __restrict__ vals)
{
  __shared__ float As[32][132];
  __shared__ float Bs[32][64];
  const int tid = threadIdx.x;
  const int bm = blockIdx.x * 128;
  const int mt = tid >> 3;
  const int nt = tid & 7;
  const int kg = tid & 7;
  const int ar = tid >> 3;
  const int n4 = (tid & 15) * 4;
  const int kr = tid >> 4;
  const float4 z4 = make_float4(0.f, 0.f, 0.f, 0.f);

  float acc[4][8];
  #pragma unroll
  for (int i = 0; i < 4; ++i)
    #pragma unroll
    for (int j = 0; j < 8; ++j) acc[i][j] = 0.f;

  for (int kc = 0; kc < 512; kc += 32) {
    __syncthreads();
    #pragma unroll
    for (int rr = 0; rr < 128; rr += 32) {
      int m = bm + ar + rr;
      float4 v = (m < NPIX) ? *(const float4*)&rpn[(size_t)m * CMID + kc + kg * 4] : z4;
      As[kg * 4 + 0][ar + rr] = v.x; As[kg * 4 + 1][ar + rr] = v.y;
      As[kg * 4 + 2][ar + rr] = v.z; As[kg * 4 + 3][ar + rr] = v.w;
    }
    *(float4*)&Bs[kr][n4]      = *(const float4*)&Wp[(kc + kr) * 64 + n4];
    *(float4*)&Bs[kr + 16][n4] = *(const float4*)&Wp[(kc + kr + 16) * 64 + n4];
    __syncthreads();
    #pragma unroll
    for (int kk = 0; kk < 32; ++kk) {
      float4 a = *(const float4*)&As[kk][mt * 4];
      float4 b0 = *(const float4*)&Bs[kk][nt * 8];
      float4 b1 = *(const float4*)&Bs[kk][nt * 8 + 4];
      float av[4] = {a.x, a.y, a.z, a.w};
      float bv[8] = {b0.x, b0.y, b0.z, b0.w, b1.x, b1.y, b1.z, b1.w};
      #pragma unroll
      for (int i = 0; i < 4; ++i)
        #pragma unroll
        for (int j = 0; j < 8; ++j) acc[i][j] = fmaf(av[i], bv[j], acc[i][j]);
    }
  }
  float bias[8];
  #pragma unroll
  for (int j = 0; j < 8; ++j) bias[j] = bp[nt * 8 + j];
  #pragma unroll
  for (int r = 0; r < 4; ++r) {
    int m = bm + mt * 4 + r;
    if (m < NPIX) {
      float o[8];
      #pragma unroll
      for (int j = 0; j < 8; ++j) o[j] = acc[r][j] + bias[j];
      float* op = vals + (size_t)m * 64 + nt * 8;
      *(float4*)op = *(float4*)&o[0];
      *(float4*)(op + 4) = *(float4*)&o[4];
    }
  }
}

// ---------------------------------------------------------------------------
// Decode: softmax + anchor decode + clip + min-size filter. 1 thread/anchor.
// ---------------------------------------------------------------------------
__global__ __launch_bounds__(256) void k_decode(
    const float* __restrict__ vals, const int* __restrict__ img,
    float* __restrict__ fg, float4* __restrict__ boxes)
{
  int gi = blockIdx.x * 256 + threadIdx.x;
  if (gi >= NANCH) return;
  const int p = gi / 9, a = gi - p * 9;
  const float AW[9] = {184.f, 368.f, 736.f, 128.f, 256.f, 512.f,  88.f, 176.f, 352.f};
  const float AH[9] = { 96.f, 192.f, 384.f, 128.f, 256.f, 512.f, 176.f, 352.f, 704.f};
  const int y = p / W_FM, x = p - y * W_FM;
  const float* row = vals + (size_t)p * 64;

  float c0 = row[2 * a], c1 = row[2 * a + 1];
  float score = 1.f / (1.f + expf(c0 - c1));

  float dxv = row[18 + 4 * a + 0];
  float dyv = row[18 + 4 * a + 1];
  float dwv = row[18 + 4 * a + 2];
  float dhv = row[18 + 4 * a + 3];

  float aw = AW[a], ah = AH[a];
  float acx = (float)(x * 16 + 8);
  float acy = (float)(y * 16 + 8);
  float pcx = dxv * aw + acx;
  float pcy = dyv * ah + acy;
  float pw = expf(dwv) * aw;
  float ph = expf(dhv) * ah;

  float imh1 = (float)img[0] - 1.f;
  float imw1 = (float)img[1] - 1.f;
  float b0 = fminf(fmaxf(pcx - 0.5f * pw, 0.f), imw1);
  float b1 = fminf(fmaxf(pcy - 0.5f * ph, 0.f), imh1);
  float b2 = fminf(fmaxf(pcx + 0.5f * pw, 0.f), imw1);
  float b3 = fminf(fmaxf(pcy + 0.5f * ph, 0.f), imh1);

  float bw = b2 - b0 + 1.f, bh = b3 - b1 + 1.f;
  if (!(bw >= 16.f && bh >= 16.f)) score = -1e9f;

  fg[gi] = score;
  boxes[gi] = make_float4(b0, b1, b2, b3);
}

// ---------------------------------------------------------------------------
// Radix-select (exact top-6000 threshold) machinery.
// ctl[0]=prefix/threshold, ctl[1]=kneed, ctl[2]=cntA, ctl[3]=cntB
// ---------------------------------------------------------------------------
__global__ void k_init(u32* __restrict__ hist, u32* __restrict__ ctl) {
  hist[threadIdx.x] = 0;
  if (threadIdx.x == 0) { ctl[0] = 0; ctl[1] = PRE_NMS_N; ctl[2] = 0; ctl[3] = 0; }
}

__global__ __launch_bounds__(256) void k_hist(
    const float* __restrict__ fg, u32* __restrict__ hist,
    const u32* __restrict__ ctl, int pass)
{
  __shared__ u32 h[256];
  h[threadIdx.x] = 0;
  __syncthreads();
  const int shift = 24 - 8 * pass;
  const u32 prefix = ctl[0];
  for (int i = blockIdx.x * 256 + threadIdx.x; i < NANCH; i += 128 * 256) {
    u32 key = fkey(fg[i]);
    bool match = (pass == 0) || ((key >> (shift + 8)) == prefix);
    if (match) atomicAdd(&h[(key >> shift) & 255], 1u);
  }
  __syncthreads();
  u32 c = h[threadIdx.x];
  if (c) atomicAdd(&hist[threadIdx.x], c);
}

__global__ void k_scan(u32* __restrict__ hist, u32* __restrict__ ctl) {
  if (threadIdx.x == 0) {
    u32 kneed = ctl[1];
    u32 cum = 0;
    int d = 0;
    for (int dd = 255; dd >= 0; --dd) {
      u32 c = hist[dd];
      if (cum + c >= kneed) { d = dd; break; }
      cum += c;
    }
    ctl[0] = (ctl[0] << 8) | (u32)d;
    ctl[1] = kneed - cum;
  }
  __syncthreads();
  hist[threadIdx.x] = 0;
}

__global__ __launch_bounds__(256) void k_compact(
    const float* __restrict__ fg, u32* __restrict__ ctl,
    u64* __restrict__ listA, u32* __restrict__ listB)
{
  int i = blockIdx.x * 256 + threadIdx.x;
  if (i >= NANCH) return;
  u32 T = ctl[0];
  u32 key = fkey(fg[i]);
  if (key > T) {
    u32 slot = atomicAdd(&ctl[2], 1u);
    listA[slot] = ((u64)key << 32) | (u64)(0xFFFFFFFFu - (u32)i);
  } else if (key == T) {
    u32 slot = atomicAdd(&ctl[3], 1u);
    if (slot < 8192) listB[slot] = (u32)i;
  }
}

__global__ __launch_bounds__(256) void k_tiefix(
    u32* __restrict__ ctl, const u32* __restrict__ listB, u64* __restrict__ listA)
{
  __shared__ u32 s[8192];
  const int tid = threadIdx.x;
  const u32 kneed = ctl[1];
  const u32 base = ctl[2];
  const u32 cntB = min(ctl[3], 8192u);
  const u32 T = ctl[0];
  if (kneed == 0) return;
  if (cntB == kneed) {
    for (u32 t = tid; t < kneed; t += 256)
      listA[base + t] = ((u64)T << 32) | (u64)(0xFFFFFFFFu - listB[t]);
    return;
  }
  u32 n2 = 1;
  while (n2 < cntB) n2 <<= 1;
  for (u32 i = tid; i < n2; i += 256) s[i] = (i < cntB) ? listB[i] : 0xFFFFFFFFu;
  __syncthreads();
  for (u32 k = 2; k <= n2; k <<= 1) {
    for (u32 j = k >> 1; j > 0; j >>= 1) {
      for (u32 i = tid; i < n2; i += 256) {
        u32 ixj = i ^ j;
        if (ixj > i) {
          u32 a = s[i], b = s[ixj];
          bool up = ((i & k) == 0);
          if ((a > b) == up) { s[i] = b; s[ixj] = a; }
        }
      }
      __syncthreads();
    }
  }
  for (u32 t = tid; t < kneed; t += 256)
    listA[base + t] = ((u64)T << 32) | (u64)(0xFFFFFFFFu - s[t]);
}

__global__ __launch_bounds__(1024) void k_sort(
    const u64* __restrict__ listA, u64* __restrict__ sorted)
{
  __shared__ u64 s[8192];
  const int tid = threadIdx.x;
  for (int i = tid; i < 8192; i += 1024) s[i] = (i < PRE_NMS_N) ? listA[i] : 0ull;
  __syncthreads();
  for (int k = 2; k <= 8192; k <<= 1) {
    for (int j = k >> 1; j > 0; j >>= 1) {
      for (int i = tid; i < 8192; i += 1024) {
        int ixj = i ^ j;
        if (ixj > i) {
          u64 a = s[i], b = s[ixj];
          bool up = ((i & k) == 0);
          if ((a < b) == up) { s[i] = b; s[ixj] = a; }
        }
      }
      __syncthreads();
    }
  }
  for (int i = tid; i < 8192; i += 1024) sorted[i] = s[i];
}

__global__ __launch_bounds__(256) void k_gather(
    const u64* __restrict__ sorted, const float4* __restrict__ boxes,
    float4* __restrict__ tb)
{
  int t = blockIdx.x * 256 + threadIdx.x;
  if (t >= PRE_NMS_N) return;
  u64 p = sorted[t];
  u32 idx = 0xFFFFFFFFu - (u32)(p & 0xFFFFFFFFull);
  tb[t] = boxes[idx];
}

// ---------------------------------------------------------------------------
// Suppression bitmask: mask[i][w] bit b == (IoU(i, w*64+b) > 0.7 && j > i)
// ---------------------------------------------------------------------------
__global__ __launch_bounds__(64) void k_mask(
    const float4* __restrict__ tb, u64* __restrict__ mask)
{
  __shared__ float4 cb[64];
  const int bj = blockIdx.x, bi = blockIdx.y, t = threadIdx.x;
  const int j0 = bj * 64;
  const int jn = min(64, PRE_NMS_N - j0);
  if (t < jn) cb[t] = tb[j0 + t];
  __syncthreads();
  const int i = bi * 64 + t;
  if (i >= PRE_NMS_N) return;
  const float4 b = tb[i];
  const float ai = (b.z - b.x + 1.f) * (b.w - b.y + 1.f);
  u64 bits = 0;
  for (int tt = 0; tt < jn; ++tt) {
    int j = j0 + tt;
    if (j <= i) continue;
    float4 c = cb[tt];
    float iw = fminf(b.z, c.z) - fmaxf(b.x, c.x) + 1.f;
    float ih = fminf(b.w, c.w) - fmaxf(b.y, c.y) + 1.f;
    float inter = fmaxf(iw, 0.f) * fmaxf(ih, 0.f);
    float aj = (c.z - c.x + 1.f) * (c.w - c.y + 1.f);
    float iou = inter / (ai + aj - inter);
    if (iou > 0.7f) bits |= (1ull << tt);
  }
  mask[(size_t)i * WPR + bj] = bits;
}

// ---------------------------------------------------------------------------
// Single-wave greedy NMS walk with register-resident removed-bitmask;
// early exit after 300 kept (only the first 300 kept reach the output).
// ---------------------------------------------------------------------------
__global__ __launch_bounds__(64) void k_nms(
    const u64* __restrict__ mask, const float* __restrict__ tb,
    const u64* __restrict__ sorted, float* __restrict__ out)
{
  const int lane = threadIdx.x;
  u64 r0 = 0, r1 = 0;   // removed words: lane -> word lane; lane -> word 64+lane
  int kept = 0;
  const u32 kcut = fkey(-1e8f);
  for (int i = 0; i < PRE_NMS_N; ++i) {
    const int w = i >> 6, b = i & 63;
    u64 v0 = shfl64(r0, w & 63);
    u64 v1 = shfl64(r1, w & 63);
    u64 word = (w < 64) ? v0 : v1;
    if (!((word >> b) & 1ull)) {
      u32 key = (u32)(sorted[i] >> 32);
      if (key <= kcut) break;          // sorted tail: all filtered -> zeros
      if (lane < 4) out[kept * 4 + lane] = tb[i * 4 + lane];
      ++kept;
      if (kept >= POST_NMS_N) break;
      const u64* row = mask + (size_t)i * WPR;
      r0 |= row[lane];
      if (lane < WPR - 64) r1 |= row[64 + lane];
    }
  }
  for (int j = kept * 4 + lane; j < POST_NMS_N * 4; j += 64) out[j] = 0.f;
}

// ---------------------------------------------------------------------------
extern "C" void kernel_launch(void* const* d_in, const int* in_sizes, int n_in,
                              void* d_out, int out_size, void* d_ws, size_t ws_size,
                              hipStream_t stream) {
  const float* fm  = (const float*)d_in[0];
  const float* Wr  = (const float*)d_in[1];
  const float* br  = (const float*)d_in[2];
  const float* Wsc = (const float*)d_in[3];
  const float* bsc = (const float*)d_in[4];
  const float* Wbb = (const float*)d_in[5];
  const float* bbb = (const float*)d_in[6];
  const int*   img = (const int*)d_in[7];
  float* out = (float*)d_out;

  char* w = (char*)d_ws;
  size_t off = 0;
  auto alloc = [&](size_t bytes) {
    size_t p = off;
    off = (off + bytes + 255) & ~(size_t)255;
    return p;
  };
  float* rpn    = (float*)(w + alloc((size_t)NPIX * CMID * 4));       // 30.72 MB
  float* fg     = (float*)(w + alloc((size_t)NANCH * 4));
  float4* boxes = (float4*)(w + alloc((size_t)NANCH * 16));
  u32* hist     = (u32*)(w + alloc(1024));
  u32* ctl      = (u32*)(w + alloc(64));
  u64* listA    = (u64*)(w + alloc((size_t)PRE_NMS_N * 8));
  u32* listB    = (u32*)(w + alloc(8192 * 4));
  u64* sorted   = (u64*)(w + alloc(8192 * 8));
  float4* topbox= (float4*)(w + alloc((size_t)PRE_NMS_N * 16));
  u64* mask     = (u64*)(w + alloc((size_t)PRE_NMS_N * WPR * 8));     // 4.5 MB
  float* zp     = (float*)(w + alloc(256));
  float* Wp     = (float*)(w + alloc(512 * 64 * 4));
  float* bp     = (float*)(w + alloc(64 * 4));
  float* vals   = (float*)(w + alloc((size_t)NPIX * 64 * 4));         // 3.84 MB
  size_t fb = (size_t)NPIX * CIN * 2;
  size_t wb = (size_t)9216 * CMID * 2;
  unsigned short* fm0 = (unsigned short*)(w + alloc(fb));
  unsigned short* fm1 = (unsigned short*)(w + alloc(fb));
  unsigned short* fm2 = (unsigned short*)(w + alloc(fb));
  unsigned short* wt0 = (unsigned short*)(w + alloc(wb));
  unsigned short* wt1 = (unsigned short*)(w + alloc(wb));
  unsigned short* wt2 = (unsigned short*)(w + alloc(wb));

  // 1. precision-split + transpose + pack
  k_split_fm<<<dim3(1024), dim3(256), 0, stream>>>(fm, fm0, fm1, fm2, zp);
  k_split_wt<<<dim3(144, 8), dim3(256), 0, stream>>>(Wr, wt0, wt1, wt2);
  k_packW<<<dim3(128), dim3(256), 0, stream>>>(Wsc, bsc, Wbb, bbb, Wp, bp);
  // 2. conv (3x3 + bias + relu), spatial-union MFMA
  k_conv5<<<dim3(120 * 4), dim3(256), 0, stream>>>(
      fm0, fm1, fm2, wt0, wt1, wt2, br, zp, rpn);
  // 3. heads + decode
  k_headgemm<<<dim3(118), dim3(256), 0, stream>>>(rpn, Wp, bp, vals);
  k_decode<<<dim3((NANCH + 255) / 256), dim3(256), 0, stream>>>(vals, img, fg, boxes);
  // 4. exact top-6000 radix select
  k_init<<<1, 256, 0, stream>>>(hist, ctl);
  for (int pass = 0; pass < 4; ++pass) {
    k_hist<<<128, 256, 0, stream>>>(fg, hist, ctl, pass);
    k_scan<<<1, 256, 0, stream>>>(hist, ctl);
  }
  k_compact<<<(NANCH + 255) / 256, 256, 0, stream>>>(fg, ctl, listA, listB);
  k_tiefix<<<1, 256, 0, stream>>>(ctl, listB, listA);
  // 5. sort (desc score, asc index) + gather
  k_sort<<<1, 1024, 0, stream>>>(listA, sorted);
  k_gather<<<(PRE_NMS_N + 255) / 256, 256, 0, stream>>>(sorted, boxes, topbox);
  // 6. NMS mask + single-wave walk + emit 300
  k_mask<<<dim3(WPR, WPR), 64, 0, stream>>>(topbox, mask);
  k_nms<<<1, 64, 0, stream>>>(mask, (const float*)topbox, sorted, out);
}